// Round 1
// baseline (6346.765 us; speedup 1.0000x reference)
//
#include <hip/hip_runtime.h>
#include <hip/hip_fp16.h>
#include <cstdint>
#include <cstddef>

typedef _Float16 f16;
typedef __attribute__((ext_vector_type(8))) _Float16 f16x8;
typedef __attribute__((ext_vector_type(4))) _Float16 f16x4;
typedef __attribute__((ext_vector_type(4))) float f32x4;

#define B_SZ 256
#define T_IN 1024
#define W_CH 512
#define U_N  512
#define P_K  16
#define TP   1009            // T_IN - P_K + 1
#define MROWS (B_SZ * TP)    // 258304

// ---------------------------------------------------------------------------
// Weight convert + transpose: fp32 [k][n] -> f16 [n][k].
// Kt: canonical k order (used by k_gemm).
// Rt: k-axis PERMUTED with pi(k) = (k & ~63) | ((k&15)<<2) | ((k>>4)&3) so the
// rnn state writes to LDS become contiguous b64 stores. MFMA result is
// invariant to a shared k-permutation of A and B.
// ---------------------------------------------------------------------------
__global__ __launch_bounds__(256) void k_convert(
    const float* __restrict__ kern, const float* __restrict__ rec,
    f16* __restrict__ Kt, f16* __restrict__ Rt) {
  int idx = blockIdx.x * 256 + threadIdx.x;   // 0 .. 2*2^18
  int which = idx >> 18;
  int e = idx & 262143;
  int n = e >> 9;
  int k = e & 511;
  if (which == 0) {
    Kt[(size_t)n * 512 + k] = (f16)kern[(size_t)k * 512 + n];
  } else {
    int kp = (k & 448) | ((k & 15) << 2) | ((k >> 4) & 3);
    Rt[(size_t)n * 512 + kp] = (f16)rec[(size_t)k * 512 + n];
  }
}

// ---------------------------------------------------------------------------
// PSC conv: syn[b,t,w] = psc_b + sum_k psc_w[k] * x[b,t+k,w]   (f16 out)
// Thread owns (b, w-quad) and marches 64 t's with a 16-deep float4 ring.
// ---------------------------------------------------------------------------
__global__ __launch_bounds__(256) void k_conv(
    const float* __restrict__ x, const float* __restrict__ psc_w,
    const float* __restrict__ psc_b, f16* __restrict__ syn) {
  int g  = blockIdx.x * 256 + threadIdx.x;
  int wq = g & 127;              // w quad (4 floats)
  int tt = (g >> 7) & 15;        // t tile of 64
  int b  = g >> 11;
  int t0 = tt * 64;
  const float4* xr = (const float4*)x + (size_t)b * T_IN * 128 + wq;
  float wgt[16];
#pragma unroll
  for (int k = 0; k < 16; ++k) wgt[k] = psc_w[k];
  float b0 = psc_b[0];
  float4 win[16];
#pragma unroll
  for (int i = 0; i < 15; ++i) win[i] = xr[(size_t)(t0 + i) * 128];
  f16* sp = syn + ((size_t)b * TP + t0) * 512 + wq * 4;
  int steps = TP - t0; if (steps > 64) steps = 64;   // wave-uniform
  for (int j0 = 0; j0 < 64; j0 += 16) {
#pragma unroll
    for (int jj = 0; jj < 16; ++jj) {
      int j = j0 + jj;
      if (j < steps) {
        win[(j + 15) & 15] = xr[(size_t)(t0 + j + 15) * 128];
        float ax = b0, ay = b0, az = b0, aw = b0;
#pragma unroll
        for (int k = 0; k < 16; ++k) {
          float4 v = win[(j + k) & 15];
          float wk = wgt[k];
          ax += wk * v.x; ay += wk * v.y; az += wk * v.z; aw += wk * v.w;
        }
        f16x4 o; o.x = (f16)ax; o.y = (f16)ay; o.z = (f16)az; o.w = (f16)aw;
        *(f16x4*)(sp + (size_t)j * 512) = o;
      }
    }
  }
}

// ---------------------------------------------------------------------------
// Xp = syn @ K + bias  (fp32 result written into d_out, overwritten later by
// the recurrent kernel in place).  128x128 tile, BK=32, mfma 16x16x32 f16.
// ---------------------------------------------------------------------------
__global__ __launch_bounds__(256) void k_gemm(
    const f16* __restrict__ syn, const f16* __restrict__ Kt,
    const float* __restrict__ bias, float* __restrict__ out) {
  int bid = blockIdx.x;
  size_t m0 = (size_t)(bid >> 2) * 128;
  int n0 = (bid & 3) * 128;
  int tid = threadIdx.x;
  int wave = tid >> 6, lane = tid & 63;
  int q = lane >> 4, l15 = lane & 15;
  __shared__ f16 lA[128 * 32];
  __shared__ f16 lB[128 * 32];
  f32x4 acc[8][2] = {};
  int s0 = tid, s1 = tid + 256;
  int rA0 = s0 >> 2, cA0 = (s0 & 3) * 8;
  int rA1 = s1 >> 2, cA1 = (s1 & 3) * 8;
  for (int k0 = 0; k0 < 512; k0 += 32) {
    f16x8 a0 = *(const f16x8*)(syn + (m0 + rA0) * 512 + k0 + cA0);
    f16x8 a1 = *(const f16x8*)(syn + (m0 + rA1) * 512 + k0 + cA1);
    f16x8 b0 = *(const f16x8*)(Kt + (size_t)(n0 + rA0) * 512 + k0 + cA0);
    f16x8 b1 = *(const f16x8*)(Kt + (size_t)(n0 + rA1) * 512 + k0 + cA1);
    __syncthreads();                       // previous tile fully consumed
    *(f16x8*)(lA + s0 * 8) = a0;  *(f16x8*)(lA + s1 * 8) = a1;
    *(f16x8*)(lB + s0 * 8) = b0;  *(f16x8*)(lB + s1 * 8) = b1;
    __syncthreads();
    f16x8 bf[2];
#pragma unroll
    for (int j = 0; j < 2; ++j)
      bf[j] = *(const f16x8*)(lB + (wave * 32 + j * 16 + l15) * 32 + q * 8);
#pragma unroll
    for (int i = 0; i < 8; ++i) {
      f16x8 af = *(const f16x8*)(lA + (i * 16 + l15) * 32 + q * 8);
      acc[i][0] = __builtin_amdgcn_mfma_f32_16x16x32_f16(af, bf[0], acc[i][0], 0, 0, 0);
      acc[i][1] = __builtin_amdgcn_mfma_f32_16x16x32_f16(af, bf[1], acc[i][1], 0, 0, 0);
    }
  }
#pragma unroll
  for (int j = 0; j < 2; ++j) {
    int col = n0 + wave * 32 + j * 16 + l15;
    float bv = bias[col];
#pragma unroll
    for (int i = 0; i < 8; ++i) {
      size_t row = m0 + i * 16 + q * 4;
#pragma unroll
      for (int r = 0; r < 4; ++r)
        out[(row + r) * 512 + col] = acc[i][j][r] + bv;
    }
  }
}

// ---------------------------------------------------------------------------
// Sequential recurrence.  32 blocks x 8 batches, 512 threads (8 waves); wave
// owns 64 output units.  R split: kk0..7 in VGPRs (128/lane), kk8..15 streamed
// from L2 with a 3-deep window.  State round-trips via DOUBLE-BUFFERED LDS in
// the pi-permuted k layout (contiguous b64 state writes).  One raw s_barrier
// per step with lgkmcnt-only drain (global n-stores are never drained
// in-loop).  Reads Xp from io (=d_out) and overwrites it with n in place.
// ---------------------------------------------------------------------------
__global__ __launch_bounds__(512, 2) void k_rnn(
    const f16* __restrict__ Rt, float* __restrict__ io) {
  int b0 = blockIdx.x * 8;
  int tid = threadIdx.x, wave = tid >> 6, lane = tid & 63;
  int q = lane >> 4, l15 = lane & 15;
  __shared__ f16 S0[16 * 520];    // state [m][kp], stride 520 halfs (1040 B)
  __shared__ f16 S1[16 * 520];    // double buffer

  for (int i = tid; i < 16 * 520; i += 512) { S0[i] = (f16)0.f; S1[i] = (f16)0.f; }

  const f16* rbase = Rt + (size_t)(wave * 64 + l15) * 512 + q * 8;
  f16x8 rs[8][4];                 // kk = 0..7 register-resident
#pragma unroll
  for (int kk = 0; kk < 8; ++kk)
#pragma unroll
    for (int nt = 0; nt < 4; ++nt)
      rs[kk][nt] = *(const f16x8*)(rbase + (size_t)nt * 8192 + kk * 32);

  bool active = (q < 2);
  float* iobase[4];
#pragma unroll
  for (int i = 0; i < 4; ++i) {
    int mm = (q * 4 + i) & 7;     // inactive lanes mirror active ones (L2 hit)
    iobase[i] = io + (size_t)(b0 + mm) * TP * 512 + wave * 64 + l15;
  }
  float xp[4][4];
#pragma unroll
  for (int i = 0; i < 4; ++i)
#pragma unroll
    for (int nt = 0; nt < 4; ++nt) xp[i][nt] = iobase[i][nt * 16];

  f16* Scur = S0;
  f16* Snxt = S1;
  __syncthreads();

  for (int t = 0; t < TP; ++t) {
    const f16* abase = Scur + l15 * 520 + q * 8;
    f32x4 acc[4] = {};
    f16x8 sw[3][4];                                   // L2 stream window
#pragma unroll
    for (int s = 0; s < 3; ++s)
#pragma unroll
      for (int nt = 0; nt < 4; ++nt)
        sw[s][nt] = *(const f16x8*)(rbase + (size_t)nt * 8192 + (8 + s) * 32);
#pragma unroll
    for (int kk = 0; kk < 8; ++kk) {                  // register-resident R
      f16x8 af = *(const f16x8*)(abase + kk * 32);
#pragma unroll
      for (int nt = 0; nt < 4; ++nt)
        acc[nt] = __builtin_amdgcn_mfma_f32_16x16x32_f16(af, rs[kk][nt], acc[nt], 0, 0, 0);
    }
#pragma unroll
    for (int kk = 8; kk < 16; ++kk) {                 // L2-streamed R
      int slot = (kk - 8) % 3;
      f16x8 af = *(const f16x8*)(abase + kk * 32);
#pragma unroll
      for (int nt = 0; nt < 4; ++nt)
        acc[nt] = __builtin_amdgcn_mfma_f32_16x16x32_f16(af, sw[slot][nt], acc[nt], 0, 0, 0);
      if (kk + 3 < 16) {
#pragma unroll
        for (int nt = 0; nt < 4; ++nt)
          sw[slot][nt] = *(const f16x8*)(rbase + (size_t)nt * 8192 + (kk + 3) * 32);
      }
    }
    // epilogue: out -> n (store), soft-reset state, b64 state write (pi layout)
#pragma unroll
    for (int i = 0; i < 4; ++i) {
      f16x4 sv;
#pragma unroll
      for (int nt = 0; nt < 4; ++nt) {
        float o  = acc[nt][i] + xp[i][nt];
        float en = __builtin_amdgcn_exp2f(-4.3280850f * o);     // exp(-3o)
        float n  = __builtin_amdgcn_rcpf(1.f + en);             // sigmoid(3o)
        float eg = __builtin_amdgcn_exp2f((2.f * n - 1.f) * 1.4426950f); // exp(2n-1)
        float g  = __builtin_amdgcn_rcpf(1.f + eg);             // sigmoid(1-2n)
        if (active) iobase[i][nt * 16] = n;                     // n overwrites Xp
        sv[nt] = (f16)(o * g);                                  // new state
      }
      if (active)   // pi layout: state[r][w*64+nt*16+l15] -> S[r][w*64+l15*4+nt]
        *(f16x4*)(Snxt + (q * 4 + i) * 520 + wave * 64 + l15 * 4) = sv;
    }
#pragma unroll
    for (int i = 0; i < 4; ++i) iobase[i] += 512;
    if (t < TP - 1) {                     // prefetch Xp[t+1] (hidden by next MFMA phase)
#pragma unroll
      for (int i = 0; i < 4; ++i)
#pragma unroll
        for (int nt = 0; nt < 4; ++nt) xp[i][nt] = iobase[i][nt * 16];
    }
    // Single barrier per step: drain LDS (state writes) only; global stores
    // are to disjoint addresses and need no in-loop drain.
    asm volatile("s_waitcnt lgkmcnt(0)\n\ts_barrier" ::: "memory");
    f16* tmpS = Scur; Scur = Snxt; Snxt = tmpS;
  }
}

// ---------------------------------------------------------------------------
extern "C" void kernel_launch(void* const* d_in, const int* in_sizes, int n_in,
                              void* d_out, int out_size, void* d_ws, size_t ws_size,
                              hipStream_t stream) {
  (void)in_sizes; (void)n_in; (void)out_size; (void)ws_size;
  const float* x     = (const float*)d_in[0];
  const float* psc_w = (const float*)d_in[1];
  const float* psc_b = (const float*)d_in[2];
  const float* kern  = (const float*)d_in[3];
  const float* rec   = (const float*)d_in[4];
  const float* bias  = (const float*)d_in[5];
  float* out = (float*)d_out;
  char* ws = (char*)d_ws;
  // ws layout: syn f16 (258304*512*2 = 264,503,296 B) | Kt f16 512KB | Rt f16 512KB
  f16* syn = (f16*)ws;
  f16* Kt  = (f16*)(ws + 264503296ull);
  f16* Rt  = (f16*)(ws + 265027584ull);

  k_convert<<<2048, 256, 0, stream>>>(kern, rec, Kt, Rt);
  k_conv   <<<2048, 256, 0, stream>>>(x, psc_w, psc_b, syn);
  k_gemm   <<<2018 * 4, 256, 0, stream>>>(syn, Kt, bias, out);
  k_rnn    <<<32, 512, 0, stream>>>(Rt, out);
}

// Round 2
// 6338.002 us; speedup vs baseline: 1.0014x; 1.0014x over previous
//
#include <hip/hip_runtime.h>
#include <hip/hip_fp16.h>
#include <cstdint>
#include <cstddef>

typedef _Float16 f16;
typedef __attribute__((ext_vector_type(8))) _Float16 f16x8;
typedef __attribute__((ext_vector_type(4))) _Float16 f16x4;
typedef __attribute__((ext_vector_type(4))) float f32x4;

#define B_SZ 256
#define T_IN 1024
#define W_CH 512
#define U_N  512
#define P_K  16
#define TP   1009            // T_IN - P_K + 1
#define MROWS (B_SZ * TP)    // 258304

// ---------------------------------------------------------------------------
// Weight convert + transpose: fp32 [k][n] -> f16 [n][k].
// Kt: canonical k order (used by k_gemm).
// Rt: k-axis PERMUTED with pi(k) = (k & ~63) | ((k&15)<<2) | ((k>>4)&3) so the
// rnn state writes to LDS become contiguous b64 stores. MFMA result is
// invariant to a shared k-permutation of A and B.
// ---------------------------------------------------------------------------
__global__ __launch_bounds__(256) void k_convert(
    const float* __restrict__ kern, const float* __restrict__ rec,
    f16* __restrict__ Kt, f16* __restrict__ Rt) {
  int idx = blockIdx.x * 256 + threadIdx.x;   // 0 .. 2*2^18
  int which = idx >> 18;
  int e = idx & 262143;
  int n = e >> 9;
  int k = e & 511;
  if (which == 0) {
    Kt[(size_t)n * 512 + k] = (f16)kern[(size_t)k * 512 + n];
  } else {
    int kp = (k & 448) | ((k & 15) << 2) | ((k >> 4) & 3);
    Rt[(size_t)n * 512 + kp] = (f16)rec[(size_t)k * 512 + n];
  }
}

// ---------------------------------------------------------------------------
// PSC conv: syn[b,t,w] = psc_b + sum_k psc_w[k] * x[b,t+k,w]   (f16 out)
// Thread owns (b, w-quad) and marches 64 t's with a 16-deep float4 ring.
// ---------------------------------------------------------------------------
__global__ __launch_bounds__(256) void k_conv(
    const float* __restrict__ x, const float* __restrict__ psc_w,
    const float* __restrict__ psc_b, f16* __restrict__ syn) {
  int g  = blockIdx.x * 256 + threadIdx.x;
  int wq = g & 127;              // w quad (4 floats)
  int tt = (g >> 7) & 15;        // t tile of 64
  int b  = g >> 11;
  int t0 = tt * 64;
  const float4* xr = (const float4*)x + (size_t)b * T_IN * 128 + wq;
  float wgt[16];
#pragma unroll
  for (int k = 0; k < 16; ++k) wgt[k] = psc_w[k];
  float b0 = psc_b[0];
  float4 win[16];
#pragma unroll
  for (int i = 0; i < 15; ++i) win[i] = xr[(size_t)(t0 + i) * 128];
  f16* sp = syn + ((size_t)b * TP + t0) * 512 + wq * 4;
  int steps = TP - t0; if (steps > 64) steps = 64;   // wave-uniform
  for (int j0 = 0; j0 < 64; j0 += 16) {
#pragma unroll
    for (int jj = 0; jj < 16; ++jj) {
      int j = j0 + jj;
      if (j < steps) {
        win[(j + 15) & 15] = xr[(size_t)(t0 + j + 15) * 128];
        float ax = b0, ay = b0, az = b0, aw = b0;
#pragma unroll
        for (int k = 0; k < 16; ++k) {
          float4 v = win[(j + k) & 15];
          float wk = wgt[k];
          ax += wk * v.x; ay += wk * v.y; az += wk * v.z; aw += wk * v.w;
        }
        f16x4 o; o.x = (f16)ax; o.y = (f16)ay; o.z = (f16)az; o.w = (f16)aw;
        *(f16x4*)(sp + (size_t)j * 512) = o;
      }
    }
  }
}

// ---------------------------------------------------------------------------
// Xp = syn @ K + bias  (fp32 result written into d_out, overwritten later by
// the recurrent kernel in place).  128x128 tile, BK=32, mfma 16x16x32 f16.
// ---------------------------------------------------------------------------
__global__ __launch_bounds__(256) void k_gemm(
    const f16* __restrict__ syn, const f16* __restrict__ Kt,
    const float* __restrict__ bias, float* __restrict__ out) {
  int bid = blockIdx.x;
  size_t m0 = (size_t)(bid >> 2) * 128;
  int n0 = (bid & 3) * 128;
  int tid = threadIdx.x;
  int wave = tid >> 6, lane = tid & 63;
  int q = lane >> 4, l15 = lane & 15;
  __shared__ f16 lA[128 * 32];
  __shared__ f16 lB[128 * 32];
  f32x4 acc[8][2] = {};
  int s0 = tid, s1 = tid + 256;
  int rA0 = s0 >> 2, cA0 = (s0 & 3) * 8;
  int rA1 = s1 >> 2, cA1 = (s1 & 3) * 8;
  for (int k0 = 0; k0 < 512; k0 += 32) {
    f16x8 a0 = *(const f16x8*)(syn + (m0 + rA0) * 512 + k0 + cA0);
    f16x8 a1 = *(const f16x8*)(syn + (m0 + rA1) * 512 + k0 + cA1);
    f16x8 b0 = *(const f16x8*)(Kt + (size_t)(n0 + rA0) * 512 + k0 + cA0);
    f16x8 b1 = *(const f16x8*)(Kt + (size_t)(n0 + rA1) * 512 + k0 + cA1);
    __syncthreads();                       // previous tile fully consumed
    *(f16x8*)(lA + s0 * 8) = a0;  *(f16x8*)(lA + s1 * 8) = a1;
    *(f16x8*)(lB + s0 * 8) = b0;  *(f16x8*)(lB + s1 * 8) = b1;
    __syncthreads();
    f16x8 bf[2];
#pragma unroll
    for (int j = 0; j < 2; ++j)
      bf[j] = *(const f16x8*)(lB + (wave * 32 + j * 16 + l15) * 32 + q * 8);
#pragma unroll
    for (int i = 0; i < 8; ++i) {
      f16x8 af = *(const f16x8*)(lA + (i * 16 + l15) * 32 + q * 8);
      acc[i][0] = __builtin_amdgcn_mfma_f32_16x16x32_f16(af, bf[0], acc[i][0], 0, 0, 0);
      acc[i][1] = __builtin_amdgcn_mfma_f32_16x16x32_f16(af, bf[1], acc[i][1], 0, 0, 0);
    }
  }
#pragma unroll
  for (int j = 0; j < 2; ++j) {
    int col = n0 + wave * 32 + j * 16 + l15;
    float bv = bias[col];
#pragma unroll
    for (int i = 0; i < 8; ++i) {
      size_t row = m0 + i * 16 + q * 4;
#pragma unroll
      for (int r = 0; r < 4; ++r)
        out[(row + r) * 512 + col] = acc[i][j][r] + bv;
    }
  }
}

// ---------------------------------------------------------------------------
// Sequential recurrence.  32 blocks x 8 batches, 512 threads (8 waves); wave
// owns 64 output units.  R split: kk0..10 register-resident (176 regs/lane,
// VGPR+AGPR), kk11..15 streamed from L2 through a 2-slot window whose loads
// are issued >=250cy before use: kk11/12 prefetched in the PREVIOUS step's
// epilogue (R is constant -- loads stay pending across the raw s_barrier,
// which only drains lgkmcnt), consumed FIRST after the barrier; refills
// kk13/14/15 issue early and are separated from their use by the kk0..10
// register-MFMA phase.  State round-trips via double-buffered LDS in the
// pi-permuted k layout (contiguous b64 state writes).  One raw s_barrier per
// step.  Reads Xp from io (=d_out), overwrites it with n in place.
// ---------------------------------------------------------------------------
__global__ __launch_bounds__(512, 2) void k_rnn(
    const f16* __restrict__ Rt, float* __restrict__ io) {
  int b0 = blockIdx.x * 8;
  int tid = threadIdx.x, wave = tid >> 6, lane = tid & 63;
  int q = lane >> 4, l15 = lane & 15;
  __shared__ f16 S[2][16 * 520];  // state [m][kp], stride 520 halfs, dbuf

  for (int i = tid; i < 16 * 520; i += 512) { S[0][i] = (f16)0.f; S[1][i] = (f16)0.f; }

  const f16* rbase = Rt + (size_t)(wave * 64 + l15) * 512 + q * 8;
  f16x8 rs[11][4];                // kk = 0..10 register-resident
#pragma unroll
  for (int kk = 0; kk < 11; ++kk)
#pragma unroll
    for (int nt = 0; nt < 4; ++nt)
      rs[kk][nt] = *(const f16x8*)(rbase + (size_t)nt * 8192 + kk * 32);

  bool active = (q < 2);
  unsigned ioff[4];               // 32-bit element offsets off uniform io base
#pragma unroll
  for (int i = 0; i < 4; ++i) {
    int mm = (q * 4 + i) & 7;     // inactive lanes mirror active ones (L2 hit)
    ioff[i] = (unsigned)(b0 + mm) * (TP * 512u) + (unsigned)(wave * 64 + l15);
  }
  float xp[4][4];
#pragma unroll
  for (int i = 0; i < 4; ++i)
#pragma unroll
    for (int nt = 0; nt < 4; ++nt) xp[i][nt] = io[ioff[i] + nt * 16u];

  // initial prefetch of the first streamed pair (kk=11,12)
  f16x8 swA[4], swB[4];
#pragma unroll
  for (int nt = 0; nt < 4; ++nt) swA[nt] = *(const f16x8*)(rbase + (size_t)nt * 8192 + 11 * 32);
#pragma unroll
  for (int nt = 0; nt < 4; ++nt) swB[nt] = *(const f16x8*)(rbase + (size_t)nt * 8192 + 12 * 32);

  int sel = 0;
  __syncthreads();

  for (int t = 0; t < TP; ++t) {
    const f16* abase = S[sel] + l15 * 520 + q * 8;
    f32x4 acc[4] = {};
    // --- kk=11 from swA (prefetched last step, fully hidden), refill kk13 ---
    {
      f16x8 af = *(const f16x8*)(abase + 11 * 32);
#pragma unroll
      for (int nt = 0; nt < 4; ++nt)
        acc[nt] = __builtin_amdgcn_mfma_f32_16x16x32_f16(af, swA[nt], acc[nt], 0, 0, 0);
#pragma unroll
      for (int nt = 0; nt < 4; ++nt) swA[nt] = *(const f16x8*)(rbase + (size_t)nt * 8192 + 13 * 32);
    }
    // --- kk=12 from swB (prefetched last step), refill kk14 ---
    {
      f16x8 af = *(const f16x8*)(abase + 12 * 32);
#pragma unroll
      for (int nt = 0; nt < 4; ++nt)
        acc[nt] = __builtin_amdgcn_mfma_f32_16x16x32_f16(af, swB[nt], acc[nt], 0, 0, 0);
#pragma unroll
      for (int nt = 0; nt < 4; ++nt) swB[nt] = *(const f16x8*)(rbase + (size_t)nt * 8192 + 14 * 32);
    }
    // --- kk=0..5 register-resident (fills the kk13/14 load latency) ---
#pragma unroll
    for (int kk = 0; kk < 6; ++kk) {
      f16x8 af = *(const f16x8*)(abase + kk * 32);
#pragma unroll
      for (int nt = 0; nt < 4; ++nt)
        acc[nt] = __builtin_amdgcn_mfma_f32_16x16x32_f16(af, rs[kk][nt], acc[nt], 0, 0, 0);
    }
    // --- kk=13 from swA (8 groups since issue), refill kk15 ---
    {
      f16x8 af = *(const f16x8*)(abase + 13 * 32);
#pragma unroll
      for (int nt = 0; nt < 4; ++nt)
        acc[nt] = __builtin_amdgcn_mfma_f32_16x16x32_f16(af, swA[nt], acc[nt], 0, 0, 0);
#pragma unroll
      for (int nt = 0; nt < 4; ++nt) swA[nt] = *(const f16x8*)(rbase + (size_t)nt * 8192 + 15 * 32);
    }
    // --- kk=14 from swB (8 groups since issue) ---
    {
      f16x8 af = *(const f16x8*)(abase + 14 * 32);
#pragma unroll
      for (int nt = 0; nt < 4; ++nt)
        acc[nt] = __builtin_amdgcn_mfma_f32_16x16x32_f16(af, swB[nt], acc[nt], 0, 0, 0);
    }
    // --- kk=6..10 register-resident (fills the kk15 load latency) ---
#pragma unroll
    for (int kk = 6; kk < 11; ++kk) {
      f16x8 af = *(const f16x8*)(abase + kk * 32);
#pragma unroll
      for (int nt = 0; nt < 4; ++nt)
        acc[nt] = __builtin_amdgcn_mfma_f32_16x16x32_f16(af, rs[kk][nt], acc[nt], 0, 0, 0);
    }
    // --- kk=15 from swA (6 groups since issue) ---
    {
      f16x8 af = *(const f16x8*)(abase + 15 * 32);
#pragma unroll
      for (int nt = 0; nt < 4; ++nt)
        acc[nt] = __builtin_amdgcn_mfma_f32_16x16x32_f16(af, swA[nt], acc[nt], 0, 0, 0);
    }
    // epilogue: out -> n (store), soft-reset state, b64 state write (pi layout)
    f16* Sn = S[sel ^ 1];
#pragma unroll
    for (int i = 0; i < 4; ++i) {
      f16x4 sv;
#pragma unroll
      for (int nt = 0; nt < 4; ++nt) {
        float o  = acc[nt][i] + xp[i][nt];
        float en = __builtin_amdgcn_exp2f(-4.3280850f * o);     // exp(-3o)
        float n  = __builtin_amdgcn_rcpf(1.f + en);             // sigmoid(3o)
        float eg = __builtin_amdgcn_exp2f((2.f * n - 1.f) * 1.4426950f); // exp(2n-1)
        float g  = __builtin_amdgcn_rcpf(1.f + eg);             // sigmoid(1-2n)
        if (active) io[ioff[i] + nt * 16u] = n;                 // n overwrites Xp
        sv[nt] = (f16)(o * g);                                  // new state
      }
      if (active)   // pi layout: state[r][w*64+nt*16+l15] -> S[r][w*64+l15*4+nt]
        *(f16x4*)(Sn + (q * 4 + i) * 520 + wave * 64 + l15 * 4) = sv;
    }
#pragma unroll
    for (int i = 0; i < 4; ++i) ioff[i] += 512u;
    if (t < TP - 1) {                     // prefetch Xp[t+1] (hidden by next MFMA phase)
#pragma unroll
      for (int i = 0; i < 4; ++i)
#pragma unroll
        for (int nt = 0; nt < 4; ++nt) xp[i][nt] = io[ioff[i] + nt * 16u];
      // prefetch next step's kk=11,12 (constant R: pending across the barrier)
#pragma unroll
      for (int nt = 0; nt < 4; ++nt) swA[nt] = *(const f16x8*)(rbase + (size_t)nt * 8192 + 11 * 32);
#pragma unroll
      for (int nt = 0; nt < 4; ++nt) swB[nt] = *(const f16x8*)(rbase + (size_t)nt * 8192 + 12 * 32);
    }
    // Single barrier per step: drain LDS (state writes) only; global stores
    // are to disjoint addresses and need no in-loop drain; stream prefetches
    // stay in flight (counted vmcnt inserted by compiler before first use).
    asm volatile("s_waitcnt lgkmcnt(0)\n\ts_barrier" ::: "memory");
    sel ^= 1;
  }
}

// ---------------------------------------------------------------------------
extern "C" void kernel_launch(void* const* d_in, const int* in_sizes, int n_in,
                              void* d_out, int out_size, void* d_ws, size_t ws_size,
                              hipStream_t stream) {
  (void)in_sizes; (void)n_in; (void)out_size; (void)ws_size;
  const float* x     = (const float*)d_in[0];
  const float* psc_w = (const float*)d_in[1];
  const float* psc_b = (const float*)d_in[2];
  const float* kern  = (const float*)d_in[3];
  const float* rec   = (const float*)d_in[4];
  const float* bias  = (const float*)d_in[5];
  float* out = (float*)d_out;
  char* ws = (char*)d_ws;
  // ws layout: syn f16 (258304*512*2 = 264,503,296 B) | Kt f16 512KB | Rt f16 512KB
  f16* syn = (f16*)ws;
  f16* Kt  = (f16*)(ws + 264503296ull);
  f16* Rt  = (f16*)(ws + 265027584ull);

  k_convert<<<2048, 256, 0, stream>>>(kern, rec, Kt, Rt);
  k_conv   <<<2048, 256, 0, stream>>>(x, psc_w, psc_b, syn);
  k_gemm   <<<2018 * 4, 256, 0, stream>>>(syn, Kt, bias, out);
  k_rnn    <<<32, 512, 0, stream>>>(Rt, out);
}

// Round 3
// 4074.041 us; speedup vs baseline: 1.5579x; 1.5557x over previous
//
#include <hip/hip_runtime.h>
#include <hip/hip_fp16.h>
#include <cstdint>
#include <cstddef>

typedef _Float16 f16;
typedef __attribute__((ext_vector_type(8))) _Float16 f16x8;
typedef __attribute__((ext_vector_type(4))) _Float16 f16x4;
typedef __attribute__((ext_vector_type(4))) float f32x4;

#define B_SZ 256
#define T_IN 1024
#define W_CH 512
#define U_N  512
#define P_K  16
#define TP   1009            // T_IN - P_K + 1
#define MROWS (B_SZ * TP)    // 258304

// ---------------------------------------------------------------------------
// Weight convert + transpose: fp32 [k][n] -> f16 [n][k].
// Kt: canonical k order (used by k_gemm).
// Rt: k-axis PERMUTED with pi(k) = (k & ~63) | ((k&15)<<2) | ((k>>4)&3) so the
// rnn state writes to LDS become contiguous b64 stores. MFMA result is
// invariant to a shared k-permutation of A and B.
// ---------------------------------------------------------------------------
__global__ __launch_bounds__(256) void k_convert(
    const float* __restrict__ kern, const float* __restrict__ rec,
    f16* __restrict__ Kt, f16* __restrict__ Rt) {
  int idx = blockIdx.x * 256 + threadIdx.x;   // 0 .. 2*2^18
  int which = idx >> 18;
  int e = idx & 262143;
  int n = e >> 9;
  int k = e & 511;
  if (which == 0) {
    Kt[(size_t)n * 512 + k] = (f16)kern[(size_t)k * 512 + n];
  } else {
    int kp = (k & 448) | ((k & 15) << 2) | ((k >> 4) & 3);
    Rt[(size_t)n * 512 + kp] = (f16)rec[(size_t)k * 512 + n];
  }
}

// ---------------------------------------------------------------------------
// PSC conv: syn[b,t,w] = psc_b + sum_k psc_w[k] * x[b,t+k,w]   (f16 out)
// Thread owns (b, w-quad) and marches 64 t's with a 16-deep float4 ring.
// ---------------------------------------------------------------------------
__global__ __launch_bounds__(256) void k_conv(
    const float* __restrict__ x, const float* __restrict__ psc_w,
    const float* __restrict__ psc_b, f16* __restrict__ syn) {
  int g  = blockIdx.x * 256 + threadIdx.x;
  int wq = g & 127;              // w quad (4 floats)
  int tt = (g >> 7) & 15;        // t tile of 64
  int b  = g >> 11;
  int t0 = tt * 64;
  const float4* xr = (const float4*)x + (size_t)b * T_IN * 128 + wq;
  float wgt[16];
#pragma unroll
  for (int k = 0; k < 16; ++k) wgt[k] = psc_w[k];
  float b0 = psc_b[0];
  float4 win[16];
#pragma unroll
  for (int i = 0; i < 15; ++i) win[i] = xr[(size_t)(t0 + i) * 128];
  f16* sp = syn + ((size_t)b * TP + t0) * 512 + wq * 4;
  int steps = TP - t0; if (steps > 64) steps = 64;   // wave-uniform
  for (int j0 = 0; j0 < 64; j0 += 16) {
#pragma unroll
    for (int jj = 0; jj < 16; ++jj) {
      int j = j0 + jj;
      if (j < steps) {
        win[(j + 15) & 15] = xr[(size_t)(t0 + j + 15) * 128];
        float ax = b0, ay = b0, az = b0, aw = b0;
#pragma unroll
        for (int k = 0; k < 16; ++k) {
          float4 v = win[(j + k) & 15];
          float wk = wgt[k];
          ax += wk * v.x; ay += wk * v.y; az += wk * v.z; aw += wk * v.w;
        }
        f16x4 o; o.x = (f16)ax; o.y = (f16)ay; o.z = (f16)az; o.w = (f16)aw;
        *(f16x4*)(sp + (size_t)j * 512) = o;
      }
    }
  }
}

// ---------------------------------------------------------------------------
// Xp = syn @ K + bias  (fp32 result written into d_out, overwritten later by
// the recurrent kernel in place).  128x128 tile, BK=32, mfma 16x16x32 f16.
// ---------------------------------------------------------------------------
__global__ __launch_bounds__(256) void k_gemm(
    const f16* __restrict__ syn, const f16* __restrict__ Kt,
    const float* __restrict__ bias, float* __restrict__ out) {
  int bid = blockIdx.x;
  size_t m0 = (size_t)(bid >> 2) * 128;
  int n0 = (bid & 3) * 128;
  int tid = threadIdx.x;
  int wave = tid >> 6, lane = tid & 63;
  int q = lane >> 4, l15 = lane & 15;
  __shared__ f16 lA[128 * 32];
  __shared__ f16 lB[128 * 32];
  f32x4 acc[8][2] = {};
  int s0 = tid, s1 = tid + 256;
  int rA0 = s0 >> 2, cA0 = (s0 & 3) * 8;
  int rA1 = s1 >> 2, cA1 = (s1 & 3) * 8;
  for (int k0 = 0; k0 < 512; k0 += 32) {
    f16x8 a0 = *(const f16x8*)(syn + (m0 + rA0) * 512 + k0 + cA0);
    f16x8 a1 = *(const f16x8*)(syn + (m0 + rA1) * 512 + k0 + cA1);
    f16x8 b0 = *(const f16x8*)(Kt + (size_t)(n0 + rA0) * 512 + k0 + cA0);
    f16x8 b1 = *(const f16x8*)(Kt + (size_t)(n0 + rA1) * 512 + k0 + cA1);
    __syncthreads();                       // previous tile fully consumed
    *(f16x8*)(lA + s0 * 8) = a0;  *(f16x8*)(lA + s1 * 8) = a1;
    *(f16x8*)(lB + s0 * 8) = b0;  *(f16x8*)(lB + s1 * 8) = b1;
    __syncthreads();
    f16x8 bf[2];
#pragma unroll
    for (int j = 0; j < 2; ++j)
      bf[j] = *(const f16x8*)(lB + (wave * 32 + j * 16 + l15) * 32 + q * 8);
#pragma unroll
    for (int i = 0; i < 8; ++i) {
      f16x8 af = *(const f16x8*)(lA + (i * 16 + l15) * 32 + q * 8);
      acc[i][0] = __builtin_amdgcn_mfma_f32_16x16x32_f16(af, bf[0], acc[i][0], 0, 0, 0);
      acc[i][1] = __builtin_amdgcn_mfma_f32_16x16x32_f16(af, bf[1], acc[i][1], 0, 0, 0);
    }
  }
#pragma unroll
  for (int j = 0; j < 2; ++j) {
    int col = n0 + wave * 32 + j * 16 + l15;
    float bv = bias[col];
#pragma unroll
    for (int i = 0; i < 8; ++i) {
      size_t row = m0 + i * 16 + q * 4;
#pragma unroll
      for (int r = 0; r < 4; ++r)
        out[(row + r) * 512 + col] = acc[i][j][r] + bv;
    }
  }
}

// ---------------------------------------------------------------------------
// Sequential recurrence, SCALED OUT: 256 blocks x 1 batch (all 256 CUs lit --
// the 32-block version ran at ~730 MHz effective clock because DPM never
// boosts a 12%-active GPU).  512 threads (8 waves); wave owns 64 output
// units.  MFMA M=16 but only row 0 is a real batch; S rows 1-15 stay zero
// (their acc contribution is exactly 0).  R split: kk0..10 register-resident,
// kk11..15 streamed from L2 with cross-step prefetch of kk11/12.  State
// round-trips via double-buffered LDS in the pi-permuted k layout (one
// contiguous b64 state write per wave).  One raw s_barrier per step.
// Reads Xp from io (=d_out), overwrites it with n in place.
// ---------------------------------------------------------------------------
__global__ __launch_bounds__(512, 2) void k_rnn(
    const f16* __restrict__ Rt, float* __restrict__ io) {
  int b = blockIdx.x;             // one batch per block
  int tid = threadIdx.x, wave = tid >> 6, lane = tid & 63;
  int q = lane >> 4, l15 = lane & 15;
  __shared__ f16 S[2][16 * 520];  // state [m][kp], stride 520 halfs, dbuf

  for (int i = tid; i < 16 * 520; i += 512) { S[0][i] = (f16)0.f; S[1][i] = (f16)0.f; }

  const f16* rbase = Rt + (size_t)(wave * 64 + l15) * 512 + q * 8;
  f16x8 rs[11][4];                // kk = 0..10 register-resident
#pragma unroll
  for (int kk = 0; kk < 11; ++kk)
#pragma unroll
    for (int nt = 0; nt < 4; ++nt)
      rs[kk][nt] = *(const f16x8*)(rbase + (size_t)nt * 8192 + kk * 32);

  bool active = (q == 0);         // only row 0 (batch b) is real
  unsigned ioff = (unsigned)b * (TP * 512u) + (unsigned)(wave * 64 + l15);
  float xp[4];
#pragma unroll
  for (int nt = 0; nt < 4; ++nt) xp[nt] = io[ioff + nt * 16u];

  // initial prefetch of the first streamed pair (kk=11,12)
  f16x8 swA[4], swB[4];
#pragma unroll
  for (int nt = 0; nt < 4; ++nt) swA[nt] = *(const f16x8*)(rbase + (size_t)nt * 8192 + 11 * 32);
#pragma unroll
  for (int nt = 0; nt < 4; ++nt) swB[nt] = *(const f16x8*)(rbase + (size_t)nt * 8192 + 12 * 32);

  int sel = 0;
  __syncthreads();

  for (int t = 0; t < TP; ++t) {
    const f16* abase = S[sel] + l15 * 520 + q * 8;
    f32x4 acc[4] = {};
    // --- kk=11 from swA (prefetched last step, fully hidden), refill kk13 ---
    {
      f16x8 af = *(const f16x8*)(abase + 11 * 32);
#pragma unroll
      for (int nt = 0; nt < 4; ++nt)
        acc[nt] = __builtin_amdgcn_mfma_f32_16x16x32_f16(af, swA[nt], acc[nt], 0, 0, 0);
#pragma unroll
      for (int nt = 0; nt < 4; ++nt) swA[nt] = *(const f16x8*)(rbase + (size_t)nt * 8192 + 13 * 32);
    }
    // --- kk=12 from swB (prefetched last step), refill kk14 ---
    {
      f16x8 af = *(const f16x8*)(abase + 12 * 32);
#pragma unroll
      for (int nt = 0; nt < 4; ++nt)
        acc[nt] = __builtin_amdgcn_mfma_f32_16x16x32_f16(af, swB[nt], acc[nt], 0, 0, 0);
#pragma unroll
      for (int nt = 0; nt < 4; ++nt) swB[nt] = *(const f16x8*)(rbase + (size_t)nt * 8192 + 14 * 32);
    }
    // --- kk=0..5 register-resident (fills the kk13/14 load latency) ---
#pragma unroll
    for (int kk = 0; kk < 6; ++kk) {
      f16x8 af = *(const f16x8*)(abase + kk * 32);
#pragma unroll
      for (int nt = 0; nt < 4; ++nt)
        acc[nt] = __builtin_amdgcn_mfma_f32_16x16x32_f16(af, rs[kk][nt], acc[nt], 0, 0, 0);
    }
    // --- kk=13 from swA (8 groups since issue), refill kk15 ---
    {
      f16x8 af = *(const f16x8*)(abase + 13 * 32);
#pragma unroll
      for (int nt = 0; nt < 4; ++nt)
        acc[nt] = __builtin_amdgcn_mfma_f32_16x16x32_f16(af, swA[nt], acc[nt], 0, 0, 0);
#pragma unroll
      for (int nt = 0; nt < 4; ++nt) swA[nt] = *(const f16x8*)(rbase + (size_t)nt * 8192 + 15 * 32);
    }
    // --- kk=14 from swB (8 groups since issue) ---
    {
      f16x8 af = *(const f16x8*)(abase + 14 * 32);
#pragma unroll
      for (int nt = 0; nt < 4; ++nt)
        acc[nt] = __builtin_amdgcn_mfma_f32_16x16x32_f16(af, swB[nt], acc[nt], 0, 0, 0);
    }
    // --- kk=6..10 register-resident (fills the kk15 load latency) ---
#pragma unroll
    for (int kk = 6; kk < 11; ++kk) {
      f16x8 af = *(const f16x8*)(abase + kk * 32);
#pragma unroll
      for (int nt = 0; nt < 4; ++nt)
        acc[nt] = __builtin_amdgcn_mfma_f32_16x16x32_f16(af, rs[kk][nt], acc[nt], 0, 0, 0);
    }
    // --- kk=15 from swA (6 groups since issue) ---
    {
      f16x8 af = *(const f16x8*)(abase + 15 * 32);
#pragma unroll
      for (int nt = 0; nt < 4; ++nt)
        acc[nt] = __builtin_amdgcn_mfma_f32_16x16x32_f16(af, swA[nt], acc[nt], 0, 0, 0);
    }
    // epilogue: only row 0 is real (i==0, q==0); rows 1-15 of S remain zero.
    f16* Sn = S[sel ^ 1];
    {
      f16x4 sv;
#pragma unroll
      for (int nt = 0; nt < 4; ++nt) {
        float o  = acc[nt][0] + xp[nt];
        float en = __builtin_amdgcn_exp2f(-4.3280850f * o);     // exp(-3o)
        float n  = __builtin_amdgcn_rcpf(1.f + en);             // sigmoid(3o)
        float eg = __builtin_amdgcn_exp2f((2.f * n - 1.f) * 1.4426950f); // exp(2n-1)
        float g  = __builtin_amdgcn_rcpf(1.f + eg);             // sigmoid(1-2n)
        if (active) io[ioff + nt * 16u] = n;                    // n overwrites Xp
        sv[nt] = (f16)(o * g);                                  // new state
      }
      if (active)   // pi layout: state[0][w*64+nt*16+l15] -> S[0][w*64+l15*4+nt]
        *(f16x4*)(Sn + wave * 64 + l15 * 4) = sv;
    }
    ioff += 512u;
    if (t < TP - 1) {                     // prefetch Xp[t+1] (hidden by next MFMA phase)
#pragma unroll
      for (int nt = 0; nt < 4; ++nt) xp[nt] = io[ioff + nt * 16u];
      // prefetch next step's kk=11,12 (constant R: pending across the barrier)
#pragma unroll
      for (int nt = 0; nt < 4; ++nt) swA[nt] = *(const f16x8*)(rbase + (size_t)nt * 8192 + 11 * 32);
#pragma unroll
      for (int nt = 0; nt < 4; ++nt) swB[nt] = *(const f16x8*)(rbase + (size_t)nt * 8192 + 12 * 32);
    }
    // Single barrier per step: drain LDS (state writes) only; global stores
    // are to disjoint addresses and need no in-loop drain; stream prefetches
    // stay in flight (counted vmcnt inserted by compiler before first use).
    asm volatile("s_waitcnt lgkmcnt(0)\n\ts_barrier" ::: "memory");
    sel ^= 1;
  }
}

// ---------------------------------------------------------------------------
extern "C" void kernel_launch(void* const* d_in, const int* in_sizes, int n_in,
                              void* d_out, int out_size, void* d_ws, size_t ws_size,
                              hipStream_t stream) {
  (void)in_sizes; (void)n_in; (void)out_size; (void)ws_size;
  const float* x     = (const float*)d_in[0];
  const float* psc_w = (const float*)d_in[1];
  const float* psc_b = (const float*)d_in[2];
  const float* kern  = (const float*)d_in[3];
  const float* rec   = (const float*)d_in[4];
  const float* bias  = (const float*)d_in[5];
  float* out = (float*)d_out;
  char* ws = (char*)d_ws;
  // ws layout: syn f16 (258304*512*2 = 264,503,296 B) | Kt f16 512KB | Rt f16 512KB
  f16* syn = (f16*)ws;
  f16* Kt  = (f16*)(ws + 264503296ull);
  f16* Rt  = (f16*)(ws + 265027584ull);

  k_convert<<<2048, 256, 0, stream>>>(kern, rec, Kt, Rt);
  k_conv   <<<2048, 256, 0, stream>>>(x, psc_w, psc_b, syn);
  k_gemm   <<<2018 * 4, 256, 0, stream>>>(syn, Kt, bias, out);
  k_rnn    <<<256, 512, 0, stream>>>(Rt, out);
}

// Round 4
// 2938.033 us; speedup vs baseline: 2.1602x; 1.3867x over previous
//
#include <hip/hip_runtime.h>
#include <hip/hip_fp16.h>
#include <cstdint>
#include <cstddef>

typedef _Float16 f16;
typedef __attribute__((ext_vector_type(8))) _Float16 f16x8;
typedef __attribute__((ext_vector_type(4))) _Float16 f16x4;
typedef __attribute__((ext_vector_type(4))) float f32x4;
typedef __attribute__((ext_vector_type(4))) unsigned int u32x4;

#define B_SZ 256
#define T_IN 1024
#define W_CH 512
#define U_N  512
#define P_K  16
#define TP   1009            // T_IN - P_K + 1
#define MROWS (B_SZ * TP)    // 258304

// ---------------------------------------------------------------------------
// Weight convert + transpose: fp32 [k][n] -> f16 [n][k].
// Kt: canonical k order (used by k_gemm).
// Rt: k-axis PERMUTED with pi(k) = (k & ~63) | ((k&15)<<2) | ((k>>4)&3) so the
// rnn state writes to LDS become contiguous b64 stores. MFMA result is
// invariant to a shared k-permutation of A and B.
// ---------------------------------------------------------------------------
__global__ __launch_bounds__(256) void k_convert(
    const float* __restrict__ kern, const float* __restrict__ rec,
    f16* __restrict__ Kt, f16* __restrict__ Rt) {
  int idx = blockIdx.x * 256 + threadIdx.x;   // 0 .. 2*2^18
  int which = idx >> 18;
  int e = idx & 262143;
  int n = e >> 9;
  int k = e & 511;
  if (which == 0) {
    Kt[(size_t)n * 512 + k] = (f16)kern[(size_t)k * 512 + n];
  } else {
    int kp = (k & 448) | ((k & 15) << 2) | ((k >> 4) & 3);
    Rt[(size_t)n * 512 + kp] = (f16)rec[(size_t)k * 512 + n];
  }
}

// ---------------------------------------------------------------------------
// PSC conv: syn[b,t,w] = psc_b + sum_k psc_w[k] * x[b,t+k,w]   (f16 out)
// Thread owns (b, w-quad) and marches 64 t's with a 16-deep float4 ring.
// ---------------------------------------------------------------------------
__global__ __launch_bounds__(256) void k_conv(
    const float* __restrict__ x, const float* __restrict__ psc_w,
    const float* __restrict__ psc_b, f16* __restrict__ syn) {
  int g  = blockIdx.x * 256 + threadIdx.x;
  int wq = g & 127;              // w quad (4 floats)
  int tt = (g >> 7) & 15;        // t tile of 64
  int b  = g >> 11;
  int t0 = tt * 64;
  const float4* xr = (const float4*)x + (size_t)b * T_IN * 128 + wq;
  float wgt[16];
#pragma unroll
  for (int k = 0; k < 16; ++k) wgt[k] = psc_w[k];
  float b0 = psc_b[0];
  float4 win[16];
#pragma unroll
  for (int i = 0; i < 15; ++i) win[i] = xr[(size_t)(t0 + i) * 128];
  f16* sp = syn + ((size_t)b * TP + t0) * 512 + wq * 4;
  int steps = TP - t0; if (steps > 64) steps = 64;   // wave-uniform
  for (int j0 = 0; j0 < 64; j0 += 16) {
#pragma unroll
    for (int jj = 0; jj < 16; ++jj) {
      int j = j0 + jj;
      if (j < steps) {
        win[(j + 15) & 15] = xr[(size_t)(t0 + j + 15) * 128];
        float ax = b0, ay = b0, az = b0, aw = b0;
#pragma unroll
        for (int k = 0; k < 16; ++k) {
          float4 v = win[(j + k) & 15];
          float wk = wgt[k];
          ax += wk * v.x; ay += wk * v.y; az += wk * v.z; aw += wk * v.w;
        }
        f16x4 o; o.x = (f16)ax; o.y = (f16)ay; o.z = (f16)az; o.w = (f16)aw;
        *(f16x4*)(sp + (size_t)j * 512) = o;
      }
    }
  }
}

// ---------------------------------------------------------------------------
// Xp = syn @ K + bias  (fp32 result written into d_out, overwritten later by
// the recurrent kernel in place).  128x128 tile, BK=32, mfma 16x16x32 f16.
// ---------------------------------------------------------------------------
__global__ __launch_bounds__(256) void k_gemm(
    const f16* __restrict__ syn, const f16* __restrict__ Kt,
    const float* __restrict__ bias, float* __restrict__ out) {
  int bid = blockIdx.x;
  size_t m0 = (size_t)(bid >> 2) * 128;
  int n0 = (bid & 3) * 128;
  int tid = threadIdx.x;
  int wave = tid >> 6, lane = tid & 63;
  int q = lane >> 4, l15 = lane & 15;
  __shared__ f16 lA[128 * 32];
  __shared__ f16 lB[128 * 32];
  f32x4 acc[8][2] = {};
  int s0 = tid, s1 = tid + 256;
  int rA0 = s0 >> 2, cA0 = (s0 & 3) * 8;
  int rA1 = s1 >> 2, cA1 = (s1 & 3) * 8;
  for (int k0 = 0; k0 < 512; k0 += 32) {
    f16x8 a0 = *(const f16x8*)(syn + (m0 + rA0) * 512 + k0 + cA0);
    f16x8 a1 = *(const f16x8*)(syn + (m0 + rA1) * 512 + k0 + cA1);
    f16x8 b0 = *(const f16x8*)(Kt + (size_t)(n0 + rA0) * 512 + k0 + cA0);
    f16x8 b1 = *(const f16x8*)(Kt + (size_t)(n0 + rA1) * 512 + k0 + cA1);
    __syncthreads();                       // previous tile fully consumed
    *(f16x8*)(lA + s0 * 8) = a0;  *(f16x8*)(lA + s1 * 8) = a1;
    *(f16x8*)(lB + s0 * 8) = b0;  *(f16x8*)(lB + s1 * 8) = b1;
    __syncthreads();
    f16x8 bf[2];
#pragma unroll
    for (int j = 0; j < 2; ++j)
      bf[j] = *(const f16x8*)(lB + (wave * 32 + j * 16 + l15) * 32 + q * 8);
#pragma unroll
    for (int i = 0; i < 8; ++i) {
      f16x8 af = *(const f16x8*)(lA + (i * 16 + l15) * 32 + q * 8);
      acc[i][0] = __builtin_amdgcn_mfma_f32_16x16x32_f16(af, bf[0], acc[i][0], 0, 0, 0);
      acc[i][1] = __builtin_amdgcn_mfma_f32_16x16x32_f16(af, bf[1], acc[i][1], 0, 0, 0);
    }
  }
#pragma unroll
  for (int j = 0; j < 2; ++j) {
    int col = n0 + wave * 32 + j * 16 + l15;
    float bv = bias[col];
#pragma unroll
    for (int i = 0; i < 8; ++i) {
      size_t row = m0 + i * 16 + q * 4;
#pragma unroll
      for (int r = 0; r < 4; ++r)
        out[(row + r) * 512 + col] = acc[i][j][r] + bv;
    }
  }
}

// ---------------------------------------------------------------------------
// Sequential recurrence.  256 blocks x 1 batch, 512 threads (8 waves, 2/SIMD);
// wave owns 64 output units.  R split (round-4): kk0..10 register-resident,
// kk11..14 in a 128KB LDS tile (staged once, XOR-swizzled -> conflict-free
// b128 reads), kk15 streamed from L2 (32KB/step, issued at step-top and
// consumed last).  This removes 128KB/CU/step of L2 traffic (the round-3
// binder: 160KB/step ~ 2,700cy at ~56B/cy/CU vs the 2,123cy step).
// State: only row 0 is real -> S holds JUST row 0, double-buffered (2KB).
// A-fragments are all-lane broadcast reads (conflict-free) + AND-mask to
// zero for lanes l15>0 (replaces the 8-way-conflicted 16-row read).
// One raw s_barrier per step.  Reads Xp from io (=d_out), overwrites with n.
// ---------------------------------------------------------------------------
__global__ __launch_bounds__(512, 2) void k_rnn(
    const f16* __restrict__ Rt, float* __restrict__ io) {
  int b = blockIdx.x;             // one batch per block
  int tid = threadIdx.x, wave = tid >> 6, lane = tid & 63;
  int q = lane >> 4, l15 = lane & 15;
  __shared__ f16 R4[4 * 512 * 32];   // kk 11..14, [g][row][32k], swizzled (128KB)
  __shared__ f16 SR[2 * 512];        // state row 0, double-buffered (2KB)

  // ---- stage R kk11..14 into LDS, swizzle: 16B slot c -> c ^ (row&3) ----
  {
    int row = tid;                   // 0..511
    const f16x8* src = (const f16x8*)(Rt + (size_t)row * 512 + 11 * 32);
#pragma unroll
    for (int g = 0; g < 4; ++g) {
      char* dst = (char*)R4 + g * 32768 + row * 64;
#pragma unroll
      for (int c = 0; c < 4; ++c)
        *(f16x8*)(dst + ((c * 16) ^ ((row & 3) << 4))) = src[g * 4 + c];
    }
    if (tid < 512) { SR[tid] = (f16)0.f; SR[512 + tid] = (f16)0.f; }
  }

  const f16* rbase = Rt + (size_t)(wave * 64 + l15) * 512 + q * 8;
  f16x8 rs[11][4];                // kk = 0..10 register-resident
#pragma unroll
  for (int kk = 0; kk < 11; ++kk)
#pragma unroll
    for (int nt = 0; nt < 4; ++nt)
      rs[kk][nt] = *(const f16x8*)(rbase + (size_t)nt * 8192 + kk * 32);

  unsigned amask = (l15 == 0) ? 0xFFFFFFFFu : 0u;   // A-row mask (rows 1-15 = 0)
  // per-lane R4 read base: row = wave*64 + l15 (+nt*16), slot q ^ (l15&3)
  const char* r4base = (const char*)R4 + (wave * 64 + l15) * 64
                       + ((q * 16) ^ ((l15 & 3) << 4));

  bool active = (q == 0);         // only C/D row 0 is real
  unsigned ioff = (unsigned)b * (TP * 512u) + (unsigned)(wave * 64 + l15);
  float xp[4];
#pragma unroll
  for (int nt = 0; nt < 4; ++nt) xp[nt] = io[ioff + nt * 16u];

  int sel = 0;
  __syncthreads();

  for (int t = 0; t < TP; ++t) {
    const f16* sb = SR + sel * 512;
    f32x4 acc[4] = {};
    // ---- issue kk15 L2 stream at step-top (consumed last: ~full step away)
    f16x8 sw[4];
#pragma unroll
    for (int nt = 0; nt < 4; ++nt)
      sw[nt] = *(const f16x8*)(rbase + (size_t)nt * 8192 + 15 * 32);
    // ---- kk 0..10: broadcast af + register-resident B ----
#pragma unroll
    for (int kk = 0; kk < 11; ++kk) {
      f16x8 av = *(const f16x8*)(sb + kk * 32 + q * 8);
      u32x4 ab = *(u32x4*)&av;  ab &= amask;
      f16x8 af = *(f16x8*)&ab;
#pragma unroll
      for (int nt = 0; nt < 4; ++nt)
        acc[nt] = __builtin_amdgcn_mfma_f32_16x16x32_f16(af, rs[kk][nt], acc[nt], 0, 0, 0);
    }
    // ---- kk 11..14: B from LDS tile (swizzled, conflict-free) ----
#pragma unroll
    for (int g = 0; g < 4; ++g) {
      f16x8 bf[4];
#pragma unroll
      for (int nt = 0; nt < 4; ++nt)
        bf[nt] = *(const f16x8*)(r4base + g * 32768 + nt * 1024);
      f16x8 av = *(const f16x8*)(sb + (11 + g) * 32 + q * 8);
      u32x4 ab = *(u32x4*)&av;  ab &= amask;
      f16x8 af = *(f16x8*)&ab;
#pragma unroll
      for (int nt = 0; nt < 4; ++nt)
        acc[nt] = __builtin_amdgcn_mfma_f32_16x16x32_f16(af, bf[nt], acc[nt], 0, 0, 0);
    }
    // ---- kk 15: streamed B ----
    {
      f16x8 av = *(const f16x8*)(sb + 15 * 32 + q * 8);
      u32x4 ab = *(u32x4*)&av;  ab &= amask;
      f16x8 af = *(f16x8*)&ab;
#pragma unroll
      for (int nt = 0; nt < 4; ++nt)
        acc[nt] = __builtin_amdgcn_mfma_f32_16x16x32_f16(af, sw[nt], acc[nt], 0, 0, 0);
    }
    // ---- epilogue: row 0 only; n -> io, new state -> SR[sel^1] ----
    f16* sn = SR + (sel ^ 1) * 512;
    {
      f16x4 sv;
#pragma unroll
      for (int nt = 0; nt < 4; ++nt) {
        float o  = acc[nt][0] + xp[nt];
        float en = __builtin_amdgcn_exp2f(-4.3280850f * o);     // exp(-3o)
        float n  = __builtin_amdgcn_rcpf(1.f + en);             // sigmoid(3o)
        float eg = __builtin_amdgcn_exp2f((2.f * n - 1.f) * 1.4426950f); // exp(2n-1)
        float g  = __builtin_amdgcn_rcpf(1.f + eg);             // sigmoid(1-2n)
        if (active) io[ioff + nt * 16u] = n;                    // n overwrites Xp
        sv[nt] = (f16)(o * g);                                  // new state
      }
      if (active)   // pi layout: unit w*64+nt*16+l15 -> position w*64+l15*4+nt
        *(f16x4*)(sn + wave * 64 + l15 * 4) = sv;
    }
    ioff += 512u;
    if (t < TP - 1) {                     // prefetch Xp[t+1]
#pragma unroll
      for (int nt = 0; nt < 4; ++nt) xp[nt] = io[ioff + nt * 16u];
    }
    // Single barrier per step: drain LDS (state write) only; global stores
    // are disjoint-address and never drained in-loop.
    asm volatile("s_waitcnt lgkmcnt(0)\n\ts_barrier" ::: "memory");
    sel ^= 1;
  }
}

// ---------------------------------------------------------------------------
extern "C" void kernel_launch(void* const* d_in, const int* in_sizes, int n_in,
                              void* d_out, int out_size, void* d_ws, size_t ws_size,
                              hipStream_t stream) {
  (void)in_sizes; (void)n_in; (void)out_size; (void)ws_size;
  const float* x     = (const float*)d_in[0];
  const float* psc_w = (const float*)d_in[1];
  const float* psc_b = (const float*)d_in[2];
  const float* kern  = (const float*)d_in[3];
  const float* rec   = (const float*)d_in[4];
  const float* bias  = (const float*)d_in[5];
  float* out = (float*)d_out;
  char* ws = (char*)d_ws;
  // ws layout: syn f16 (258304*512*2 = 264,503,296 B) | Kt f16 512KB | Rt f16 512KB
  f16* syn = (f16*)ws;
  f16* Kt  = (f16*)(ws + 264503296ull);
  f16* Rt  = (f16*)(ws + 265027584ull);

  k_convert<<<2048, 256, 0, stream>>>(kern, rec, Kt, Rt);
  k_conv   <<<2048, 256, 0, stream>>>(x, psc_w, psc_b, syn);
  k_gemm   <<<2018 * 4, 256, 0, stream>>>(syn, Kt, bias, out);
  k_rnn    <<<256, 512, 0, stream>>>(Rt, out);
}